// Round 1
// baseline (257.224 us; speedup 1.0000x reference)
//
#include <hip/hip_runtime.h>
#include <hip/hip_bf16.h>

#define BATCH  4096
#define UNITS  1024
#define CDIM   2048   // K = UNITS + IN_DIM
#define NDIM   4096   // 4 * UNITS (f, i, c, o)

typedef __attribute__((ext_vector_type(8))) short bf16x8;
typedef __attribute__((ext_vector_type(4))) float f32x4;

__device__ __forceinline__ void gload_lds16(const void* g, void* l) {
    __builtin_amdgcn_global_load_lds(
        (const __attribute__((address_space(1))) unsigned int*)g,
        (__attribute__((address_space(3))) unsigned int*)l, 16, 0, 0);
}

__device__ __forceinline__ float bf2f(unsigned short u) {
    union { unsigned int i; float f; } v; v.i = ((unsigned int)u) << 16; return v.f;
}

// ---- concat(hidden, inputs) -> bf16 x [BATCH, CDIM] -------------------------
__global__ void cast_x(const float* __restrict__ h, const float* __restrict__ in,
                       __hip_bfloat16* __restrict__ x) {
    int t = blockIdx.x * blockDim.x + threadIdx.x;   // 4 elems per thread
    int col = (t % (CDIM / 4)) * 4;
    int row = t / (CDIM / 4);
    const float* src = (col < UNITS) ? (h + (size_t)row * UNITS + col)
                                     : (in + (size_t)row * UNITS + (col - UNITS));
    float4 v = *(const float4*)src;
    __hip_bfloat16* dst = x + (size_t)row * CDIM + col;
    dst[0] = __float2bfloat16(v.x); dst[1] = __float2bfloat16(v.y);
    dst[2] = __float2bfloat16(v.z); dst[3] = __float2bfloat16(v.w);
}

// ---- transpose-cast four W [CDIM, UNITS] f32 -> Wt [NDIM, CDIM] bf16 --------
// Wt row n = gate*UNITS + u holds W_gate[:, u] along k (B^T layout for GEMM).
__global__ void cast_w(const float* __restrict__ Wf, const float* __restrict__ Wi,
                       const float* __restrict__ Wc, const float* __restrict__ Wo,
                       __hip_bfloat16* __restrict__ Wt) {
    __shared__ float tile[32][33];
    int g = blockIdx.z;
    const float* W = (g == 0) ? Wf : (g == 1) ? Wi : (g == 2) ? Wc : Wo;
    int u0 = blockIdx.x * 32, k0 = blockIdx.y * 32;
    int tx = threadIdx.x, ty = threadIdx.y;          // block (32, 8)
#pragma unroll
    for (int r = 0; r < 4; ++r)
        tile[ty + r * 8][tx] = W[(size_t)(k0 + ty + r * 8) * UNITS + u0 + tx];
    __syncthreads();
#pragma unroll
    for (int r = 0; r < 4; ++r) {
        int u = u0 + ty + r * 8;
        Wt[(size_t)(g * UNITS + u) * CDIM + k0 + tx] = __float2bfloat16(tile[tx][ty + r * 8]);
    }
}

// ---- concat biases -> bias_all[NDIM] ----------------------------------------
__global__ void prep_bias(const float* __restrict__ bf_, const float* __restrict__ bi_,
                          const float* __restrict__ bc_, const float* __restrict__ bo_,
                          float* __restrict__ bias) {
    int t = blockIdx.x * blockDim.x + threadIdx.x;   // NDIM threads
    const float* b = (t < 1024) ? bf_ : (t < 2048) ? bi_ : (t < 3072) ? bc_ : bo_;
    bias[t] = b[t & 1023];
}

// ---- GEMM: Z[M,N] = A[M,K] * Bt[N,K]^T + bias, bf16 in/out, fp32 accum ------
// m97 structure: 128x128 tile, BK=32, 4 waves each 64x64 (4x4 of 16x16x32 MFMA)
__global__ __launch_bounds__(256) void gemm_bt(
    const __hip_bfloat16* __restrict__ A,    // [BATCH, CDIM]
    const __hip_bfloat16* __restrict__ Bt,   // [NDIM, CDIM]
    const float* __restrict__ bias,          // [NDIM]
    __hip_bfloat16* __restrict__ Z)          // [BATCH, NDIM]
{
    __shared__ short As[128 * 32];
    __shared__ short Bs[128 * 32];
    const int K = CDIM;
    int m0 = blockIdx.y * 128, n0 = blockIdx.x * 128;
    int tid  = threadIdx.x;
    int w    = tid >> 6, lane = tid & 63;
    int quad = lane >> 4, r16 = lane & 15;
    int wm = (w & 1) * 64, wn = (w >> 1) * 64;

    f32x4 acc[4][4];
#pragma unroll
    for (int i = 0; i < 4; ++i)
#pragma unroll
        for (int j = 0; j < 4; ++j) acc[i][j] = (f32x4){0.f, 0.f, 0.f, 0.f};

    const short* Ag = (const short*)A  + (size_t)m0 * K;
    const short* Bg = (const short*)Bt + (size_t)n0 * K;

    for (int k0 = 0; k0 < K; k0 += 32) {
        __syncthreads();                      // prev iter's ds_reads done
#pragma unroll
        for (int j = 0; j < 2; ++j) {
            int l   = j * 256 + tid;          // 512 chunks of 16B per 8KB tile
            int row = l >> 2, ch = l & 3;     // 4 x 16B per 32-elem row
            int lofs = (j * 256 + w * 64) * 8;  // wave-uniform LDS base (shorts)
            gload_lds16(Ag + (size_t)row * K + k0 + ch * 8, As + lofs);
            gload_lds16(Bg + (size_t)row * K + k0 + ch * 8, Bs + lofs);
        }
        asm volatile("s_waitcnt vmcnt(0)" ::: "memory");
        __syncthreads();

        bf16x8 af[4], bfr[4];
#pragma unroll
        for (int i = 0; i < 4; ++i)
            af[i]  = *(const bf16x8*)&As[(wm + i * 16 + r16) * 32 + quad * 8];
#pragma unroll
        for (int j = 0; j < 4; ++j)
            bfr[j] = *(const bf16x8*)&Bs[(wn + j * 16 + r16) * 32 + quad * 8];
#pragma unroll
        for (int i = 0; i < 4; ++i)
#pragma unroll
            for (int j = 0; j < 4; ++j)
                acc[i][j] = __builtin_amdgcn_mfma_f32_16x16x32_bf16(af[i], bfr[j], acc[i][j], 0, 0, 0);
    }

    // epilogue: C/D layout col=lane&15, row=quad*4+reg (m89-verified)
#pragma unroll
    for (int j = 0; j < 4; ++j) {
        int n = n0 + wn + j * 16 + r16;
        float bv = bias[n];
#pragma unroll
        for (int i = 0; i < 4; ++i) {
            f32x4 v = acc[i][j];
#pragma unroll
            for (int rr = 0; rr < 4; ++rr) {
                int m = m0 + wm + i * 16 + quad * 4 + rr;
                Z[(size_t)m * NDIM + n] = __float2bfloat16(v[rr] + bv);
            }
        }
    }
}

// ---- gates: f,i,c,o -> new_cell, new_hidden ---------------------------------
__global__ void lstm_gates(const __hip_bfloat16* __restrict__ Z,
                           const float* __restrict__ cell,
                           float* __restrict__ out) {
    int t = blockIdx.x * blockDim.x + threadIdx.x;   // 4 elems per thread
    int col = (t % (UNITS / 4)) * 4;
    int row = t / (UNITS / 4);
    const unsigned short* zr = (const unsigned short*)Z + (size_t)row * NDIM + col;
    float4 cv = *(const float4*)(cell + (size_t)row * UNITS + col);
    float cvv[4] = {cv.x, cv.y, cv.z, cv.w};
    float nh[4], nc[4];
#pragma unroll
    for (int e = 0; e < 4; ++e) {
        float zf = bf2f(zr[e]);
        float zi = bf2f(zr[1024 + e]);
        float zc = bf2f(zr[2048 + e]);
        float zo = bf2f(zr[3072 + e]);
        float f = 1.f / (1.f + __expf(-zf));
        float i = 1.f / (1.f + __expf(-zi));
        float cc = tanhf(zc);
        float o = 1.f / (1.f + __expf(-zo));
        float c = f * cvv[e] + i * cc;
        nc[e] = c;
        nh[e] = o * tanhf(c);
    }
    float* oh = out + (size_t)row * UNITS + col;
    float* oc = out + (size_t)BATCH * UNITS + (size_t)row * UNITS + col;
    *(float4*)oh = make_float4(nh[0], nh[1], nh[2], nh[3]);
    *(float4*)oc = make_float4(nc[0], nc[1], nc[2], nc[3]);
}

extern "C" void kernel_launch(void* const* d_in, const int* in_sizes, int n_in,
                              void* d_out, int out_size, void* d_ws, size_t ws_size,
                              hipStream_t stream) {
    const float* inputs = (const float*)d_in[0];
    const float* hidden = (const float*)d_in[1];
    const float* cell   = (const float*)d_in[2];
    const float* Wf = (const float*)d_in[3];
    const float* bf_ = (const float*)d_in[4];
    const float* Wi = (const float*)d_in[5];
    const float* bi_ = (const float*)d_in[6];
    const float* Wc = (const float*)d_in[7];
    const float* bc_ = (const float*)d_in[8];
    const float* Wo = (const float*)d_in[9];
    const float* bo_ = (const float*)d_in[10];
    float* out = (float*)d_out;

    char* ws = (char*)d_ws;
    __hip_bfloat16* x    = (__hip_bfloat16*)ws;                          // 16 MB
    __hip_bfloat16* Wt   = (__hip_bfloat16*)(ws + (16u << 20));          // 16 MB
    float*          bias = (float*)(ws + (32u << 20));                   // 16 KB
    __hip_bfloat16* Z    = (__hip_bfloat16*)(ws + (32u << 20) + (1u << 16)); // 32 MB

    // 1) concat + cast x: 4096*2048/4 threads
    cast_x<<<dim3((BATCH * CDIM / 4) / 256), dim3(256), 0, stream>>>(hidden, inputs, x);
    // 2) transpose-cast weights
    cast_w<<<dim3(UNITS / 32, CDIM / 32, 4), dim3(32, 8), 0, stream>>>(Wf, Wi, Wc, Wo, Wt);
    // 3) biases
    prep_bias<<<dim3(NDIM / 256), dim3(256), 0, stream>>>(bf_, bi_, bc_, bo_, bias);
    // 4) fused 4-gate GEMM [4096,2048]x[2048,4096]
    gemm_bt<<<dim3(NDIM / 128, BATCH / 128), dim3(256), 0, stream>>>(x, Wt, bias, Z);
    // 5) elementwise LSTM update
    lstm_gates<<<dim3((BATCH * UNITS / 4) / 256), dim3(256), 0, stream>>>(Z, cell, out);
}

// Round 2
// 222.212 us; speedup vs baseline: 1.1576x; 1.1576x over previous
//
#include <hip/hip_runtime.h>
#include <hip/hip_bf16.h>

#define BATCH  4096
#define UNITS  1024
#define CDIM   2048   // K = UNITS + IN_DIM
#define NDIM   4096   // 4 * UNITS (f, i, c, o)

typedef __attribute__((ext_vector_type(8))) short bf16x8;
typedef __attribute__((ext_vector_type(4))) float f32x4;

__device__ __forceinline__ void gload_lds16(const void* g, void* l) {
    __builtin_amdgcn_global_load_lds(
        (const __attribute__((address_space(1))) unsigned int*)g,
        (__attribute__((address_space(3))) unsigned int*)l, 16, 0, 0);
}

__device__ __forceinline__ float sigm(float x) { return 1.f / (1.f + __expf(-x)); }
__device__ __forceinline__ float tanh_fast(float x) { return 2.f / (1.f + __expf(-2.f * x)) - 1.f; }

// ---- prep: concat-cast x AND transpose-cast-permute weights in one launch ---
// Wt row layout (gate-interleaved so the GEMM epilogue needs no shuffles):
//   n(u,g) = (u>>5)*128 + ((u>>4)&1)*64 + g*16 + (u&15)
// i.e. within each 128-row block: wave0 j-tiles = gates 0..3 @ units [0,16),
//                                 wave1 j-tiles = gates 0..3 @ units [16,32).
__global__ void prep(const float* __restrict__ h, const float* __restrict__ in,
                     const float* __restrict__ Wf, const float* __restrict__ Wi,
                     const float* __restrict__ Wc, const float* __restrict__ Wo,
                     __hip_bfloat16* __restrict__ x, __hip_bfloat16* __restrict__ Wt) {
    __shared__ float tile[32][33];
    int b = blockIdx.x, tid = threadIdx.x;
    if (b < (BATCH * CDIM / 4) / 256) {
        // concat(hidden, inputs) -> bf16 x [BATCH, CDIM]
        int t = b * 256 + tid;
        int col = (t % (CDIM / 4)) * 4;
        int row = t / (CDIM / 4);
        const float* src = (col < UNITS) ? (h + (size_t)row * UNITS + col)
                                         : (in + (size_t)row * UNITS + (col - UNITS));
        float4 v = *(const float4*)src;
        __hip_bfloat16* dst = x + (size_t)row * CDIM + col;
        dst[0] = __float2bfloat16(v.x); dst[1] = __float2bfloat16(v.y);
        dst[2] = __float2bfloat16(v.z); dst[3] = __float2bfloat16(v.w);
    } else {
        // transpose-cast W_g[CDIM, UNITS] -> permuted Wt[NDIM, CDIM]
        int idx = b - 8192;
        int g = idx >> 11, rest = idx & 2047, ky = rest >> 5, ux = rest & 31;
        const float* W = (g == 0) ? Wf : (g == 1) ? Wi : (g == 2) ? Wc : Wo;
        int u0 = ux * 32, k0 = ky * 32;
        int tx = tid & 31, ty = tid >> 5;          // (32, 8)
#pragma unroll
        for (int r = 0; r < 4; ++r)
            tile[ty + r * 8][tx] = W[(size_t)(k0 + ty + r * 8) * UNITS + u0 + tx];
        __syncthreads();
#pragma unroll
        for (int r = 0; r < 4; ++r) {
            int u = u0 + ty + r * 8;
            int n = ((u >> 5) << 7) + (((u >> 4) & 1) << 6) + (g << 4) + (u & 15);
            Wt[(size_t)n * CDIM + k0 + tx] = __float2bfloat16(tile[tx][ty + r * 8]);
        }
    }
}

// ---- fused GEMM + LSTM gates --------------------------------------------------
// Z = x @ Wt^T (+bias) for all 4 gates; epilogue computes new_cell/new_hidden.
// 128x128 tile, BK=64 (32 barriers), XOR-swizzled LDS (conflict-free ds_read_b128),
// global_load_lds width-16 staging, mfma_f32_16x16x32_bf16.
__global__ __launch_bounds__(256) void gemm_lstm(
    const __hip_bfloat16* __restrict__ A,    // [BATCH, CDIM]
    const __hip_bfloat16* __restrict__ Bt,   // [NDIM, CDIM], gate-interleaved rows
    const float* __restrict__ b_f, const float* __restrict__ b_i,
    const float* __restrict__ b_c, const float* __restrict__ b_o,
    const float* __restrict__ cell,          // [BATCH, UNITS]
    float* __restrict__ out)                 // [2, BATCH, UNITS]: hidden, cell
{
    __shared__ short As[128 * 64];
    __shared__ short Bs[128 * 64];
    const int K = CDIM;
    int m0 = blockIdx.y * 128, n0 = blockIdx.x * 128;
    int tid  = threadIdx.x;
    int w    = tid >> 6, lane = tid & 63;
    int quad = lane >> 4, r16 = lane & 15;
    int wm = (w & 1) * 64, wn = (w >> 1) * 64;

    f32x4 acc[4][4];
#pragma unroll
    for (int i = 0; i < 4; ++i)
#pragma unroll
        for (int j = 0; j < 4; ++j) acc[i][j] = (f32x4){0.f, 0.f, 0.f, 0.f};

    const short* Ag = (const short*)A  + (size_t)m0 * K;
    const short* Bg = (const short*)Bt + (size_t)n0 * K;

    for (int k0 = 0; k0 < K; k0 += 64) {
        __syncthreads();                      // prev iter's ds_reads done
        // stage 128x64 bf16 tiles: 4 passes x 256 lanes x 16B each, per tile.
        // LDS chunk c holds global chunk c ^ (row&7)  (bank-conflict-free reads)
#pragma unroll
        for (int p = 0; p < 4; ++p) {
            int s   = p * 256 + tid;          // chunk slot: row = s>>3, c = s&7
            int row = s >> 3;
            int cg  = (s & 7) ^ (row & 7);    // swizzled *global* chunk
            int lofs = (p * 256 + w * 64) * 8;  // wave-uniform LDS base (shorts)
            gload_lds16(Ag + (size_t)row * K + k0 + cg * 8, As + lofs);
            gload_lds16(Bg + (size_t)row * K + k0 + cg * 8, Bs + lofs);
        }
        asm volatile("s_waitcnt vmcnt(0)" ::: "memory");
        __syncthreads();

#pragma unroll
        for (int ks = 0; ks < 2; ++ks) {
            bf16x8 af[4], bfr[4];
#pragma unroll
            for (int i = 0; i < 4; ++i) {
                int r = wm + i * 16 + r16;
                af[i]  = *(const bf16x8*)&As[r * 64 + (((quad + ks * 4) ^ (r16 & 7)) * 8)];
            }
#pragma unroll
            for (int j = 0; j < 4; ++j) {
                int r = wn + j * 16 + r16;
                bfr[j] = *(const bf16x8*)&Bs[r * 64 + (((quad + ks * 4) ^ (r16 & 7)) * 8)];
            }
#pragma unroll
            for (int i = 0; i < 4; ++i)
#pragma unroll
                for (int j = 0; j < 4; ++j)
                    acc[i][j] = __builtin_amdgcn_mfma_f32_16x16x32_bf16(af[i], bfr[j], acc[i][j], 0, 0, 0);
        }
    }

    // ---- fused epilogue: j-tile j == gate j at unit u (same u for all j) ----
    // C/D layout: col=lane&15, row=quad*4+reg (m89-verified)
    int u = blockIdx.x * 32 + (w >> 1) * 16 + r16;
    float bfv = b_f[u], biv = b_i[u], bcv = b_c[u], bov = b_o[u];
    float* out_h = out;
    float* out_c = out + (size_t)BATCH * UNITS;
#pragma unroll
    for (int i = 0; i < 4; ++i) {
#pragma unroll
        for (int rr = 0; rr < 4; ++rr) {
            int m = m0 + wm + i * 16 + quad * 4 + rr;
            float fg = sigm(acc[i][0][rr] + bfv);
            float ig = sigm(acc[i][1][rr] + biv);
            float cc = tanh_fast(acc[i][2][rr] + bcv);
            float og = sigm(acc[i][3][rr] + bov);
            float cold = cell[(size_t)m * UNITS + u];
            float cn = fg * cold + ig * cc;
            out_h[(size_t)m * UNITS + u] = og * tanh_fast(cn);
            out_c[(size_t)m * UNITS + u] = cn;
        }
    }
}

extern "C" void kernel_launch(void* const* d_in, const int* in_sizes, int n_in,
                              void* d_out, int out_size, void* d_ws, size_t ws_size,
                              hipStream_t stream) {
    const float* inputs = (const float*)d_in[0];
    const float* hidden = (const float*)d_in[1];
    const float* cell   = (const float*)d_in[2];
    const float* Wf = (const float*)d_in[3];
    const float* bf_ = (const float*)d_in[4];
    const float* Wi = (const float*)d_in[5];
    const float* bi_ = (const float*)d_in[6];
    const float* Wc = (const float*)d_in[7];
    const float* bc_ = (const float*)d_in[8];
    const float* Wo = (const float*)d_in[9];
    const float* bo_ = (const float*)d_in[10];
    float* out = (float*)d_out;

    char* ws = (char*)d_ws;
    __hip_bfloat16* x  = (__hip_bfloat16*)ws;                  // 16 MB
    __hip_bfloat16* Wt = (__hip_bfloat16*)(ws + (16u << 20));  // 16 MB

    // 1) concat-cast x (8192 blocks) + transpose-cast-permute W (8192 blocks)
    prep<<<dim3(16384), dim3(256), 0, stream>>>(hidden, inputs, Wf, Wi, Wc, Wo, x, Wt);
    // 2) fused 4-gate GEMM + LSTM gate math
    gemm_lstm<<<dim3(NDIM / 128, BATCH / 128), dim3(256), 0, stream>>>(
        x, Wt, bf_, bi_, bc_, bo_, cell, out);
}